// Round 9
// baseline (370.370 us; speedup 1.0000x reference)
//
#include <hip/hip_runtime.h>
#include <stdint.h>

// SIREN MLP 3->256->256->256->256->3, N=524288, fp32 in/out.
// R9: 256 threads / 4 waves / 64 pts, waves tile a 2x2 (chan-half x pt-half)
// grid: each wave owns 128 chans x 32 pts -> reads only its pt-half of h
// (16 KB/layer, was 32). Per block-layer LDS 160->96 KB at unchanged MFMA.
// Final layer fused into layer-3 epilogue in fp32 (W4 f32x4 from L1,
// shfl_xor(32) + 1.5KB LDS reduce, coalesced 192-thread store).
// Hidden layers: mfma_32x32x16_bf16, W streamed global->VGPR (64-reg
// rotating pair buffer, cross-layer prefetch), bias rides MFMA C-input.

typedef float    f32x4  __attribute__((ext_vector_type(4)));
typedef float    f32x16 __attribute__((ext_vector_type(16)));
typedef short    s16x8  __attribute__((ext_vector_type(8)));
typedef uint32_t u32x2  __attribute__((ext_vector_type(2)));
typedef uint32_t u32x4  __attribute__((ext_vector_type(4)));

#define INV2PI 0.15915494309189535f
#define L0SCALE 4.774648292756860f   /* 30/(2*pi) */

__device__ __forceinline__ uint16_t f32_to_bf16(float f) {
    uint32_t u = __builtin_bit_cast(uint32_t, f);
    u += 0x7FFFu + ((u >> 16) & 1u);   // RNE
    return (uint16_t)(u >> 16);
}
__device__ __forceinline__ uint32_t pack_bf16x2(float lo, float hi) {
#if __has_builtin(__builtin_amdgcn_cvt_pk_bf16_f32)
    auto v = __builtin_amdgcn_cvt_pk_bf16_f32(lo, hi);   // lo -> low half
    return __builtin_bit_cast(uint32_t, v);
#else
    uint32_t a = __builtin_bit_cast(uint32_t, lo);
    uint32_t b = __builtin_bit_cast(uint32_t, hi);
    a += 0x7FFFu + ((a >> 16) & 1u);
    b += 0x7FFFu + ((b >> 16) & 1u);
    return (a >> 16) | (b & 0xFFFF0000u);
#endif
}
// sin with input in REVOLUTIONS (v_sin_f32); 1/(2pi) pre-folded into weights.
__device__ __forceinline__ float sin_rev(float r) {
    return __builtin_amdgcn_sinf(r);
}

// W1..W3 -> bf16 32x32x16 A-frag order, scaled by 1/(2pi):
//   A[m=lane&31][k=(lane>>5)*8+j]; chan c = cb*32+(lane&31),
//   k = kc16*16+(lane>>5)*8+j
//   hw idx = (((l*16+kc16)*8 + cb)*64 + lane)*8 + j
__global__ void convert_weights(const float* __restrict__ W1,
                                const float* __restrict__ W2,
                                const float* __restrict__ W3,
                                uint16_t* __restrict__ wsb) {
    int tid = blockIdx.x * blockDim.x + threadIdx.x;   // 0..196607
    int l = tid >> 16;
    int r = tid & 65535;
    int c = r >> 8;        // out-chan
    int k = r & 255;       // in-chan
    const float* W = (l == 0) ? W1 : (l == 1) ? W2 : W3;
    int kc16 = k >> 4, cb = c >> 5;
    int lane = (c & 31) | (((k >> 3) & 1) << 5);
    int j = k & 7;
    wsb[(((l * 16 + kc16) * 8 + cb) * 64 + lane) * 8 + j] =
        f32_to_bf16(W[c * 256 + k] * INV2PI);
}

// 256 threads = 4 waves, 64 points/block. Wave (cw = wid>>1, pw = wid&1)
// owns chans cw*128..+127 (4 tiles of 32) x pts pw*32..+31 (1 tile).
__global__ __launch_bounds__(256, 3) void siren_main(
    const float* __restrict__ x,
    const float* __restrict__ W0, const float* __restrict__ b0,
    const float* __restrict__ b1, const float* __restrict__ b2,
    const float* __restrict__ b3,
    const float* __restrict__ W4, const float* __restrict__ b4,
    const uint16_t* __restrict__ Wb,   // permuted W1..W3, 384KB
    float* __restrict__ out)
{
    __shared__ uint16_t h_lds[2048 * 8];   // 32 KB; unit u = 16B

    const int tid  = threadIdx.x;
    const int lane = tid & 63;
    const int wid  = tid >> 6;     // 0..3
    const int cw   = wid >> 1;     // chan-half
    const int pw   = wid & 1;      // pt-half
    const int n16  = lane & 15;
    const int q    = lane >> 4;
    const int lam  = lane & 31;
    const int hi   = lane >> 5;
    const int p0   = blockIdx.x * 64;

    // rotating kc16-pair double buffer of W A-frags (64 VGPRs), hoisted
    // across layers. Preload layer-0 pair 0 (hidden under layer-0 VALU).
    s16x8 Wbuf[2][2][4];   // [buf][kc-in-pair][chan-tile]
    #pragma unroll
    for (int kc2 = 0; kc2 < 2; ++kc2)
        #pragma unroll
        for (int t = 0; t < 4; ++t)
            Wbuf[0][kc2][t] = *(const s16x8*)(Wb +
                ((kc2 * 8 + cw * 4 + t) * 64 + lane) * 8);

    // ------- Layer 0 (fp32): h1 = sin_rev( (30/2pi)*(W0 x + b0) ) ----------
    {
        float xv[4][3];
        #pragma unroll
        for (int rt = 0; rt < 4; ++rt) {
            const float* xp = x + (p0 + rt * 16 + n16) * 3;
            xv[rt][0] = xp[0]; xv[rt][1] = xp[1]; xv[rt][2] = xp[2];
        }
        #pragma unroll
        for (int oo = 0; oo < 2; ++oo) {
            const int octet = wid * 8 + oo * 4 + q;      // chan-octet 0..31
            const float* w0r = W0 + octet * 24;
            float wv[24];
            #pragma unroll
            for (int i = 0; i < 24; ++i) wv[i] = w0r[i] * L0SCALE;
            float bb[8];
            #pragma unroll
            for (int i = 0; i < 8; ++i) bb[i] = b0[octet * 8 + i] * L0SCALE;
            #pragma unroll
            for (int rt = 0; rt < 4; ++rt) {
                u32x4 pk;
                #pragma unroll
                for (int j2 = 0; j2 < 4; ++j2) {
                    float za = wv[(2*j2  )*3+0] * xv[rt][0] +
                               wv[(2*j2  )*3+1] * xv[rt][1] +
                               wv[(2*j2  )*3+2] * xv[rt][2] + bb[2*j2];
                    float zb = wv[(2*j2+1)*3+0] * xv[rt][0] +
                               wv[(2*j2+1)*3+1] * xv[rt][1] +
                               wv[(2*j2+1)*3+2] * xv[rt][2] + bb[2*j2+1];
                    pk[j2] = pack_bf16x2(sin_rev(za), sin_rev(zb));
                }
                // unit for (pt = rt*16+n16, octet): chans octet*8..+7
                const int pt = rt * 16 + n16;
                const int u = ((octet >> 1) * 2 + (pt >> 5)) * 64
                            + (octet & 1) * 32 + (pt & 31);
                *(u32x4*)&h_lds[u * 8] = pk;
            }
        }
    }
    __syncthreads();

    // ------- Hidden layers (bf16 MFMA 32x32x16, D[chan][pt]) ----------------
    #pragma unroll
    for (int l = 0; l < 3; ++l) {
        const float* bl = (l == 0) ? b1 : (l == 1) ? b2 : b3;

        // acc init = bias (pre-scaled): rides the MFMA C input.
        // elem r of tile t: chan = cw*128 + t*32 + 8*(r>>2) + 4*hi + (r&3)
        f32x16 acc[4];        // [chan-tile t], pt-tile fixed = pw
        #pragma unroll
        for (int t = 0; t < 4; ++t)
            #pragma unroll
            for (int g = 0; g < 4; ++g) {
                f32x4 bv = *(const f32x4*)&bl[cw * 128 + t * 32 + g * 8 + hi * 4];
                bv *= INV2PI;
                #pragma unroll
                for (int i = 0; i < 4; ++i) acc[t][g * 4 + i] = bv[i];
            }

        #pragma unroll
        for (int kp = 0; kp < 8; ++kp) {      // kc16 pairs
            const int cur = kp & 1, nxt = cur ^ 1;
            if (kp < 7) {                     // prefetch this layer's next pair
                #pragma unroll
                for (int kc2 = 0; kc2 < 2; ++kc2)
                    #pragma unroll
                    for (int t = 0; t < 4; ++t)
                        Wbuf[nxt][kc2][t] = *(const s16x8*)(Wb +
                            (((l * 16 + kp * 2 + 2 + kc2) * 8 + cw * 4 + t) * 64 + lane) * 8);
            } else if (l < 2) {               // prefetch NEXT layer's pair 0
                #pragma unroll
                for (int kc2 = 0; kc2 < 2; ++kc2)
                    #pragma unroll
                    for (int t = 0; t < 4; ++t)
                        Wbuf[nxt][kc2][t] = *(const s16x8*)(Wb +
                            ((((l + 1) * 16 + kc2) * 8 + cw * 4 + t) * 64 + lane) * 8);
            }
            #pragma unroll
            for (int kc2 = 0; kc2 < 2; ++kc2) {
                const int kc16 = kp * 2 + kc2;
                // B-frag for OUR pt-half only: lam = pt-in-tile, hi = k-octet
                s16x8 hf = *(const s16x8*)&h_lds[((kc16 * 2 + pw) * 64 + lane) * 8];
                #pragma unroll
                for (int t = 0; t < 4; ++t)
                    acc[t] = __builtin_amdgcn_mfma_f32_32x32x16_bf16(
                        Wbuf[cur][kc2][t], hf, acc[t], 0, 0, 0);
            }
        }
        __syncthreads();   // all h reads done before overwrite

        if (l < 2) {
            // epilogue: sin, write h_next in B-frag layout.
            // value r of tile t: chan = cw*128+t*32+8*(r>>2)+4*hi+(r&3),
            // pt = pw*32+lam -> unit u, b64 half selected by hi.
            uint32_t* hw = (uint32_t*)h_lds;
            #pragma unroll
            for (int t = 0; t < 4; ++t)
                #pragma unroll
                for (int g = 0; g < 4; ++g) {
                    float v0 = sin_rev(acc[t][g * 4 + 0]);
                    float v1 = sin_rev(acc[t][g * 4 + 1]);
                    float v2 = sin_rev(acc[t][g * 4 + 2]);
                    float v3 = sin_rev(acc[t][g * 4 + 3]);
                    const int kc16p = cw * 8 + t * 2 + (g >> 1);
                    const int u = (kc16p * 2 + pw) * 64 + (g & 1) * 32 + lam;
                    u32x2 w2 = { pack_bf16x2(v0, v1), pack_bf16x2(v2, v3) };
                    *(u32x2*)&hw[u * 4 + hi * 2] = w2;
                }
            __syncthreads();
        } else {
            // fused final layer, fp32: out[pt][o] = sum_chan W4[o][chan]*sin(acc)
            float po0 = 0.f, po1 = 0.f, po2 = 0.f;
            #pragma unroll
            for (int t = 0; t < 4; ++t)
                #pragma unroll
                for (int g = 0; g < 4; ++g) {
                    f32x4 sv;
                    #pragma unroll
                    for (int i = 0; i < 4; ++i)
                        sv[i] = sin_rev(acc[t][g * 4 + i]);
                    const int base = cw * 128 + t * 32 + g * 8 + hi * 4;
                    f32x4 w0v = *(const f32x4*)&W4[0 * 256 + base];
                    f32x4 w1v = *(const f32x4*)&W4[1 * 256 + base];
                    f32x4 w2v = *(const f32x4*)&W4[2 * 256 + base];
                    #pragma unroll
                    for (int i = 0; i < 4; ++i) {
                        po0 += w0v[i] * sv[i];
                        po1 += w1v[i] * sv[i];
                        po2 += w2v[i] * sv[i];
                    }
                }
            // fold the hi halves (lane ^ 32 holds the other 4-chan slice)
            po0 += __shfl_xor(po0, 32, 64);
            po1 += __shfl_xor(po1, 32, 64);
            po2 += __shfl_xor(po2, 32, 64);
            // cross-wave (chan-half) reduce via tiny LDS overlay
            float* red = (float*)h_lds;   // [cw][pt][o] = [2][64][3] floats
            if (hi == 0) {
                const int pt = pw * 32 + lam;
                red[cw * 192 + pt * 3 + 0] = po0;
                red[cw * 192 + pt * 3 + 1] = po1;
                red[cw * 192 + pt * 3 + 2] = po2;
            }
            __syncthreads();
            if (tid < 192) {
                const int o = tid - (tid / 3) * 3;
                out[p0 * 3 + tid] = red[tid] + red[192 + tid] + b4[o];
            }
        }
    }
}

extern "C" void kernel_launch(void* const* d_in, const int* in_sizes, int n_in,
                              void* d_out, int out_size, void* d_ws, size_t ws_size,
                              hipStream_t stream) {
    const float* x  = (const float*)d_in[0];
    const float* W0 = (const float*)d_in[1];
    const float* b0 = (const float*)d_in[2];
    const float* W1 = (const float*)d_in[3];
    const float* b1 = (const float*)d_in[4];
    const float* W2 = (const float*)d_in[5];
    const float* b2 = (const float*)d_in[6];
    const float* W3 = (const float*)d_in[7];
    const float* b3 = (const float*)d_in[8];
    const float* W4 = (const float*)d_in[9];
    const float* b4 = (const float*)d_in[10];
    float* outp     = (float*)d_out;
    uint16_t* wsb   = (uint16_t*)d_ws;   // 384KB

    hipLaunchKernelGGL(convert_weights, dim3(768), dim3(256), 0, stream,
                       W1, W2, W3, wsb);
    hipLaunchKernelGGL(siren_main, dim3(8192), dim3(256), 0, stream,
                       x, W0, b0, b1, b2, b3, W4, b4, wsb, outp);
}

// Round 10
// 304.361 us; speedup vs baseline: 1.2169x; 1.2169x over previous
//
#include <hip/hip_runtime.h>
#include <stdint.h>

// SIREN MLP 3->256->256->256->256->3, N=524288, fp32 in/out.
// R10 = R7 (32x32x16 MFMA, 4 waves x 64 chans x 64 pts, n_p=1 so W is read
// exactly once per block-layer, bias in MFMA C) + TRIPLE-buffered W
// prefetch: rolling slot g=l*8+kp (mod 3), distance 2 kc-pairs (~256 cyc
// cover vs ~200 cyc L2 latency; the old distance-1 gave only ~128).

typedef float    f32x4  __attribute__((ext_vector_type(4)));
typedef float    f32x16 __attribute__((ext_vector_type(16)));
typedef short    s16x8  __attribute__((ext_vector_type(8)));
typedef uint32_t u32x2  __attribute__((ext_vector_type(2)));
typedef uint32_t u32x4  __attribute__((ext_vector_type(4)));

#define INV2PI 0.15915494309189535f
#define L0SCALE 4.774648292756860f   /* 30/(2*pi) */
#define W4OFF 196608                 /* halfword offset of W4^T frag in ws */

__device__ __forceinline__ uint16_t f32_to_bf16(float f) {
    uint32_t u = __builtin_bit_cast(uint32_t, f);
    u += 0x7FFFu + ((u >> 16) & 1u);   // RNE
    return (uint16_t)(u >> 16);
}
__device__ __forceinline__ uint32_t pack_bf16x2(float lo, float hi) {
#if __has_builtin(__builtin_amdgcn_cvt_pk_bf16_f32)
    auto v = __builtin_amdgcn_cvt_pk_bf16_f32(lo, hi);   // lo -> low half
    return __builtin_bit_cast(uint32_t, v);
#else
    uint32_t a = __builtin_bit_cast(uint32_t, lo);
    uint32_t b = __builtin_bit_cast(uint32_t, hi);
    a += 0x7FFFu + ((a >> 16) & 1u);
    b += 0x7FFFu + ((b >> 16) & 1u);
    return (a >> 16) | (b & 0xFFFF0000u);
#endif
}
// sin with input in REVOLUTIONS (v_sin_f32); 1/(2pi) pre-folded into weights.
__device__ __forceinline__ float sin_rev(float r) {
    return __builtin_amdgcn_sinf(r);
}

// W1..W3 -> bf16 32x32x16 A-frag order, scaled by 1/(2pi):
//   A[m=lane&31][k=(lane>>5)*8+j]; chan c = cb*32+(lane&31),
//   k = kc16*16+(lane>>5)*8+j
//   hw idx = (((l*16+kc16)*8 + cb)*64 + lane)*8 + j
// W4 (3x256) -> zero-padded 16x16x32 B-frag:
//   hw idx = W4OFF + (kk*64+lane)*8 + j; val = n16<3 ? W4[n16][kk*32+q*8+j] : 0
__global__ void convert_weights(const float* __restrict__ W1,
                                const float* __restrict__ W2,
                                const float* __restrict__ W3,
                                const float* __restrict__ W4,
                                uint16_t* __restrict__ wsb) {
    int tid = blockIdx.x * blockDim.x + threadIdx.x;
    if (tid < 196608) {
        int l = tid >> 16;
        int r = tid & 65535;
        int c = r >> 8;        // out-chan
        int k = r & 255;       // in-chan
        const float* W = (l == 0) ? W1 : (l == 1) ? W2 : W3;
        int kc16 = k >> 4, cb = c >> 5;
        int lane = (c & 31) | (((k >> 3) & 1) << 5);
        int j = k & 7;
        wsb[(((l * 16 + kc16) * 8 + cb) * 64 + lane) * 8 + j] =
            f32_to_bf16(W[c * 256 + k] * INV2PI);
    } else if (tid < 200704) {
        int e = tid - 196608;              // 0..4095
        int kk = e >> 9, lane = (e >> 3) & 63, j = e & 7;
        int n16 = lane & 15, q = lane >> 4;
        float v = (n16 < 3) ? W4[n16 * 256 + kk * 32 + q * 8 + j] : 0.0f;
        wsb[W4OFF + (kk * 64 + lane) * 8 + j] = f32_to_bf16(v);
    }
}

// 256 threads = 4 waves, 64 points/block. Wave wid owns chans wid*64..+63
// (2 chan-tiles of 32) x all 64 pts (2 pt-tiles of 32). acc 2x2xf32x16.
__global__ __launch_bounds__(256, 3) void siren_main(
    const float* __restrict__ x,
    const float* __restrict__ W0, const float* __restrict__ b0,
    const float* __restrict__ b1, const float* __restrict__ b2,
    const float* __restrict__ b3,
    const float* __restrict__ b4,
    const uint16_t* __restrict__ Wb,   // permuted W1..W3 + W4 frag
    float* __restrict__ out)
{
    __shared__ uint16_t h_lds[2048 * 8];   // 32 KB; unit u = 16B

    const int tid  = threadIdx.x;
    const int lane = tid & 63;
    const int wid  = tid >> 6;
    const int n16  = lane & 15;
    const int q    = lane >> 4;
    const int lam  = lane & 31;
    const int hi   = lane >> 5;
    const int p0   = blockIdx.x * 64;

    // triple-buffered rotating W A-frag pipeline, slot = global pair idx % 3.
    // Preload pairs g=0,1 of layer 0 (latency hidden under layer-0 VALU).
    s16x8 Wbuf[3][2][2];   // [slot][kc-in-pair][chan-tile] = 48 VGPRs
    #pragma unroll
    for (int g = 0; g < 2; ++g)
        #pragma unroll
        for (int kc2 = 0; kc2 < 2; ++kc2)
            #pragma unroll
            for (int t = 0; t < 2; ++t)
                Wbuf[g][kc2][t] = *(const s16x8*)(Wb +
                    (((g * 2 + kc2) * 8 + wid * 2 + t) * 64 + lane) * 8);

    // ------- Layer 0 (fp32): h1 = sin_rev( (30/2pi)*(W0 x + b0) ) ----------
    {
        float xv[4][3];
        #pragma unroll
        for (int rt = 0; rt < 4; ++rt) {
            const float* xp = x + (p0 + rt * 16 + n16) * 3;
            xv[rt][0] = xp[0]; xv[rt][1] = xp[1]; xv[rt][2] = xp[2];
        }
        #pragma unroll
        for (int oo = 0; oo < 2; ++oo) {
            const int octet = wid * 8 + oo * 4 + q;      // chan-octet 0..31
            const float* w0r = W0 + octet * 24;
            float wv[24];
            #pragma unroll
            for (int i = 0; i < 24; ++i) wv[i] = w0r[i] * L0SCALE;
            float bb[8];
            #pragma unroll
            for (int i = 0; i < 8; ++i) bb[i] = b0[octet * 8 + i] * L0SCALE;
            #pragma unroll
            for (int rt = 0; rt < 4; ++rt) {
                u32x4 pk;
                #pragma unroll
                for (int j2 = 0; j2 < 4; ++j2) {
                    float za = wv[(2*j2  )*3+0] * xv[rt][0] +
                               wv[(2*j2  )*3+1] * xv[rt][1] +
                               wv[(2*j2  )*3+2] * xv[rt][2] + bb[2*j2];
                    float zb = wv[(2*j2+1)*3+0] * xv[rt][0] +
                               wv[(2*j2+1)*3+1] * xv[rt][1] +
                               wv[(2*j2+1)*3+2] * xv[rt][2] + bb[2*j2+1];
                    pk[j2] = pack_bf16x2(sin_rev(za), sin_rev(zb));
                }
                // unit for (pt = rt*16+n16, octet): chans octet*8..+7
                const int pt = rt * 16 + n16;
                const int u = ((octet >> 1) * 2 + (pt >> 5)) * 64
                            + (octet & 1) * 32 + (pt & 31);
                *(u32x4*)&h_lds[u * 8] = pk;
            }
        }
    }
    __syncthreads();

    // ------- Hidden layers (bf16 MFMA 32x32x16, D[chan][pt]) ----------------
    #pragma unroll
    for (int l = 0; l < 3; ++l) {
        const float* bl = (l == 0) ? b1 : (l == 1) ? b2 : b3;

        // acc init = bias (pre-scaled): rides the MFMA C input.
        // elem r of tile t: chan = wid*64 + t*32 + (r&3) + 8*(r>>2) + 4*hi
        f32x16 acc[2][2];     // [chan-tile t][pt-tile s]
        #pragma unroll
        for (int t = 0; t < 2; ++t)
            #pragma unroll
            for (int g = 0; g < 4; ++g) {
                f32x4 bv = *(const f32x4*)&bl[wid * 64 + t * 32 + g * 8 + hi * 4];
                bv *= INV2PI;
                #pragma unroll
                for (int i = 0; i < 4; ++i) {
                    acc[t][0][g * 4 + i] = bv[i];
                    acc[t][1][g * 4 + i] = bv[i];
                }
            }

        #pragma unroll
        for (int kp = 0; kp < 8; ++kp) {      // kc16 pairs
            const int g   = l * 8 + kp;       // global pair index 0..23
            const int cur = g % 3;
            if (g + 2 < 24) {                 // prefetch pair g+2 (dist 2)
                const int gn = g + 2;
                const int ns = gn % 3;
                const int nl = gn >> 3, nkp = gn & 7;
                #pragma unroll
                for (int kc2 = 0; kc2 < 2; ++kc2)
                    #pragma unroll
                    for (int t = 0; t < 2; ++t)
                        Wbuf[ns][kc2][t] = *(const s16x8*)(Wb +
                            (((nl * 16 + nkp * 2 + kc2) * 8 + wid * 2 + t) * 64 + lane) * 8);
            }
            #pragma unroll
            for (int kc2 = 0; kc2 < 2; ++kc2) {
                const int kc16 = kp * 2 + kc2;
                s16x8 hf[2];   // B-frags: lane lam = pt-in-tile, hi = k-octet
                #pragma unroll
                for (int s = 0; s < 2; ++s)
                    hf[s] = *(const s16x8*)&h_lds[((kc16 * 2 + s) * 64 + lane) * 8];
                #pragma unroll
                for (int t = 0; t < 2; ++t)
                    #pragma unroll
                    for (int s = 0; s < 2; ++s)
                        acc[t][s] = __builtin_amdgcn_mfma_f32_32x32x16_bf16(
                            Wbuf[cur][kc2][t], hf[s], acc[t][s], 0, 0, 0);
            }
        }
        __syncthreads();   // all h reads done before overwrite

        // epilogue: sin, write h_next in B-frag layout.
        // value r of tile (t,s): chan = wid*64+t*32+8*(r>>2)+4*hi+(r&3),
        // pt = s*32+lam -> unit u, b64 half selected by hi.
        uint32_t* hw = (uint32_t*)h_lds;
        #pragma unroll
        for (int t = 0; t < 2; ++t)
            #pragma unroll
            for (int s = 0; s < 2; ++s)
                #pragma unroll
                for (int g = 0; g < 4; ++g) {
                    float v0 = sin_rev(acc[t][s][g * 4 + 0]);
                    float v1 = sin_rev(acc[t][s][g * 4 + 1]);
                    float v2 = sin_rev(acc[t][s][g * 4 + 2]);
                    float v3 = sin_rev(acc[t][s][g * 4 + 3]);
                    const int kc16p = wid * 4 + t * 2 + (g >> 1);
                    const int u = (kc16p * 2 + s) * 64 + (g & 1) * 32 + lam;
                    u32x2 w2 = { pack_bf16x2(v0, v1), pack_bf16x2(v2, v3) };
                    *(u32x2*)&hw[u * 4 + hi * 2] = w2;
                }
        __syncthreads();
    }

    // ------- Final layer via 16x16x32 MFMA: out = W4 h4 + b4 ----------------
    // A = h4 (m = pt within wave's 16, k = chan), B = W4^T frag.
    {
        float bb4 = (n16 < 3) ? b4[n16] : 0.0f;
        f32x4 accF = { bb4, bb4, bb4, bb4 };
        #pragma unroll
        for (int kk = 0; kk < 8; ++kk) {
            s16x8 w4f = *(const s16x8*)(Wb + W4OFF + (kk * 64 + lane) * 8);
            // chan k = kk*32 + q*8 + j -> kc16 = kk*2+(q>>1), octet-half q&1;
            // pt = wid*16 + n16 -> s = wid>>1, pt&31 = (wid&1)*16+n16
            const int u = ((kk * 2 + (q >> 1)) * 2 + (wid >> 1)) * 64
                        + (q & 1) * 32 + (wid & 1) * 16 + n16;
            s16x8 af = *(const s16x8*)&h_lds[u * 8];
            accF = __builtin_amdgcn_mfma_f32_16x16x32_bf16(af, w4f, accF, 0, 0, 0);
        }
        // D: row=q*4+r -> pt = wid*16+q*4+r, col=n16 -> out-chan (3 used)
        if (n16 < 3) {
            #pragma unroll
            for (int r = 0; r < 4; ++r)
                out[(p0 + wid * 16 + q * 4 + r) * 3 + n16] = accF[r];
        }
    }
}

extern "C" void kernel_launch(void* const* d_in, const int* in_sizes, int n_in,
                              void* d_out, int out_size, void* d_ws, size_t ws_size,
                              hipStream_t stream) {
    const float* x  = (const float*)d_in[0];
    const float* W0 = (const float*)d_in[1];
    const float* b0 = (const float*)d_in[2];
    const float* W1 = (const float*)d_in[3];
    const float* b1 = (const float*)d_in[4];
    const float* W2 = (const float*)d_in[5];
    const float* b2 = (const float*)d_in[6];
    const float* W3 = (const float*)d_in[7];
    const float* b3 = (const float*)d_in[8];
    const float* W4 = (const float*)d_in[9];
    const float* b4 = (const float*)d_in[10];
    float* outp     = (float*)d_out;
    uint16_t* wsb   = (uint16_t*)d_ws;   // needs 402 KB

    hipLaunchKernelGGL(convert_weights, dim3(784), dim3(256), 0, stream,
                       W1, W2, W3, W4, wsb);
    hipLaunchKernelGGL(siren_main, dim3(8192), dim3(256), 0, stream,
                       x, W0, b0, b1, b2, b3, b4, wsb, outp);
}